// Round 2
// baseline (120.275 us; speedup 1.0000x reference)
//
#include <hip/hip_runtime.h>
#include <math.h>

#define N_RAYS 65536
#define T_SAMPLES 128
#define HID 16

#define RAYS_PER_BLOCK 64
#define CHUNKS 8
#define CHUNK_LEN (T_SAMPLES / CHUNKS)   // 16

// log2(e)
#define L2E 1.4426950408889634f

// block=512 (8 waves, one 16-sample chunk each), min 6 waves/EU -> VGPR cap ~85:
// 3 blocks/CU = 24 waves/CU = 6 waves/SIMD (was 4). The t-loop is pure compute:
// all 16 noise rows for the chunk are preloaded into registers (uniform row
// index -> SALU addressing), so the unrolled loop has no VMEM and no address
// VALU, and the scheduler can overlap one sample's trans tail with the next
// sample's independent j-loop across 6 resident waves.
__global__ __launch_bounds__(512, 6) void radiance_kernel(
    const float* __restrict__ o,
    const float* __restrict__ d,
    const float* __restrict__ tnear,
    const float* __restrict__ tfar,
    const float* __restrict__ noise,
    const float* __restrict__ W1,
    const float* __restrict__ b1,
    const float* __restrict__ w_sigma,
    const float* __restrict__ W_rgb,
    float* __restrict__ out)
{
    const int lane  = threadIdx.x & 63;   // ray within block (wave-coherent)
    const int chunk = threadIdx.x >> 6;   // 0..7 (one wave per chunk)
    const int ray   = blockIdx.x * RAYS_PER_BLOCK + lane;

    const int t0 = chunk * CHUNK_LEN;
    const float* __restrict__ nrow = noise + ray;

    // ---- preload ALL noise for this chunk (issued before setup; latency
    // hides under the ~100-instruction per-ray setup) ----
    const float nz0 = nrow[(size_t)t0 * N_RAYS];
    float nz[CHUNK_LEN];
#pragma unroll
    for (int i = 0; i < CHUNK_LEN; ++i) {
        int row = t0 + 1 + i;                      // wave-uniform
        if (row > T_SAMPLES - 1) row = T_SAMPLES - 1;  // only chunk 7's last (unused)
        nz[i] = nrow[(size_t)row * N_RAYS];
    }

    // ---- per-ray setup (duplicated across the 8 chunk-waves; cheap) ----
    const float ox = o[ray*3+0], oy = o[ray*3+1], oz = o[ray*3+2];
    const float dx = d[ray*3+0], dy = d[ray*3+1], dz = d[ray*3+2];
    const float tn = tnear[ray];
    const float tf = tfar[ray];
    const float dnorm = sqrtf(dx*dx + dy*dy + dz*dz);
    const float rdn   = 1.0f / dnorm;
    const float sc    = (tf - tn) * (1.0f / (float)T_SAMPLES);

    // Work in scaled time u = ts*dnorm: delta*dnorm becomes a plain subtract.
    const float scd = sc * dnorm;
    const float tnd = tn * dnorm;
    const float uf  = tf * dnorm;

    // Hoisted MLP layer 1 in scaled time: h_j(u) = relu(A_j + u*Bp_j)
    float A[HID], Bp[HID];
#pragma unroll
    for (int j = 0; j < HID; ++j) {
        const float w0 = W1[0*HID + j], w1 = W1[1*HID + j], w2 = W1[2*HID + j];
        A[j]  = fmaf(ox, w0, fmaf(oy, w1, fmaf(oz, w2, b1[j])));
        Bp[j] = fmaf(dx, w0, fmaf(dy, w1, dz * w2)) * rdn;
    }
    // Output weights: uniform-indexed -> scalar loads -> SGPRs
    float WS[HID], WR[HID], WG[HID], WB[HID];
#pragma unroll
    for (int j = 0; j < HID; ++j) {
        WS[j] = w_sigma[j];
        WR[j] = W_rgb[j*3+0];
        WG[j] = W_rgb[j*3+1];
        WB[j] = W_rgb[j*3+2];
    }

    // ---- this thread's sample chunk [t0, t0+CHUNK_LEN): pure compute ----
    float u    = fmaf(scd, (float)t0 + nz0, tnd);   // ts0 * dnorm
    float base = fmaf(scd, (float)(t0 + 1), tnd);   // bin edge t+1 (scaled)

    float lt = 1.0f;   // local transmittance within chunk
    float cr = 0.f, cg = 0.f, cb = 0.f, cd = 0.f, ca = 0.f;

#pragma unroll
    for (int i = 0; i < CHUNK_LEN; ++i) {
        // next sample position (scaled); global last sample closes at tfar
        float u_next = fmaf(scd, nz[i], base);
        if (i == CHUNK_LEN - 1 && chunk == CHUNKS - 1) u_next = uf; // slot 15 only
        base += scd;

        float sp = 0.f, rr = 0.f, gg = 0.f, bb = 0.f;
#pragma unroll
        for (int j = 0; j < HID; ++j) {
            const float h = fmaxf(fmaf(u, Bp[j], A[j]), 0.0f);
            sp = fmaf(h, WS[j], sp);
            rr = fmaf(h, WR[j], rr);
            gg = fmaf(h, WG[j], gg);
            bb = fmaf(h, WB[j], bb);
        }

        // l2 = log2(1 + exp(sp)) (stable softplus in base-2)
        const float e  = __builtin_amdgcn_exp2f(-fabsf(sp) * L2E);
        const float l2 = fmaf(fmaxf(sp, 0.0f), L2E,
                              __builtin_amdgcn_logf(1.0f + e));
        const float dd = u_next - u;             // delta * dnorm
        const float et = __builtin_amdgcn_exp2f(-dd * l2);

        // sigmoids via base-2
        const float r = __builtin_amdgcn_rcpf(1.0f + __builtin_amdgcn_exp2f(-rr * L2E));
        const float g = __builtin_amdgcn_rcpf(1.0f + __builtin_amdgcn_exp2f(-gg * L2E));
        const float b = __builtin_amdgcn_rcpf(1.0f + __builtin_amdgcn_exp2f(-bb * L2E));

        const float w = fmaf(-et, lt, lt);       // lt * (1 - et)
        cr = fmaf(w, r, cr);
        cg = fmaf(w, g, cg);
        cb = fmaf(w, b, cb);
        cd = fmaf(w, u, cd);                     // scaled depth (u = ts*dnorm)
        ca += w;
        lt *= et;
        u = u_next;
    }

    // ---- combine chunks: out_c scaled by product of previous chunks' lt ----
    __shared__ float s_lt[CHUNKS][RAYS_PER_BLOCK];
    __shared__ float s_acc[CHUNKS][5][RAYS_PER_BLOCK];
    s_lt[chunk][lane] = lt;
    s_acc[chunk][0][lane] = cr;
    s_acc[chunk][1][lane] = cg;
    s_acc[chunk][2][lane] = cb;
    s_acc[chunk][3][lane] = cd;
    s_acc[chunk][4][lane] = ca;
    __syncthreads();

    if (chunk == 0) {
        float scale = 1.0f;
        float a0 = 0.f, a1 = 0.f, a2 = 0.f, a3 = 0.f, a4 = 0.f;
#pragma unroll
        for (int c = 0; c < CHUNKS; ++c) {
            a0 = fmaf(scale, s_acc[c][0][lane], a0);
            a1 = fmaf(scale, s_acc[c][1][lane], a1);
            a2 = fmaf(scale, s_acc[c][2][lane], a2);
            a3 = fmaf(scale, s_acc[c][3][lane], a3);
            a4 = fmaf(scale, s_acc[c][4][lane], a4);
            scale *= s_lt[c][lane];
        }
        out[ray*5+0] = a0;
        out[ray*5+1] = a1;
        out[ray*5+2] = a2;
        out[ray*5+3] = a3 * rdn;   // un-scale depth back to ts units
        out[ray*5+4] = a4;
    }
}

extern "C" void kernel_launch(void* const* d_in, const int* in_sizes, int n_in,
                              void* d_out, int out_size, void* d_ws, size_t ws_size,
                              hipStream_t stream) {
    const float* o       = (const float*)d_in[0];
    const float* d       = (const float*)d_in[1];
    const float* tnear   = (const float*)d_in[2];
    const float* tfar    = (const float*)d_in[3];
    const float* noise   = (const float*)d_in[4];
    const float* W1      = (const float*)d_in[5];
    const float* b1      = (const float*)d_in[6];
    const float* w_sigma = (const float*)d_in[7];
    const float* W_rgb   = (const float*)d_in[8];
    float* out = (float*)d_out;

    dim3 block(64 * CHUNKS);                       // 512
    dim3 grid(N_RAYS / RAYS_PER_BLOCK);            // 1024
    hipLaunchKernelGGL(radiance_kernel, grid, block, 0, stream,
                       o, d, tnear, tfar, noise, W1, b1, w_sigma, W_rgb, out);
}

// Round 3
// 112.758 us; speedup vs baseline: 1.0667x; 1.0667x over previous
//
#include <hip/hip_runtime.h>
#include <math.h>

#define N_RAYS 65536
#define T_SAMPLES 128
#define HID 16
#define HPAIR (HID/2)

#define RAYS_PER_BLOCK 64
#define CHUNKS 4
#define CHUNK_LEN (T_SAMPLES / CHUNKS)   // 32
#define PF 4                             // noise prefetch depth == unroll factor

// log2(e)
#define L2E 1.4426950408889634f

typedef float v2f __attribute__((ext_vector_type(2)));

// block=256 (4 waves), min 4 waves/EU -> VGPR cap 128: proven regime where the
// allocator keeps A/B live across the t-loop (tighter caps trigger
// rematerialization + load-sinking: round-2 measured VGPR=36, kernel 43->53us).
// The j-loop runs on packed 2-wide f32 VOP3P (v_pk_fma_f32/v_pk_max_f32):
// 8 float2 pairs x 6 pk-ops = ~52 issue slots vs 96 scalar.
__global__ __launch_bounds__(256, 4) void radiance_kernel(
    const float* __restrict__ o,
    const float* __restrict__ d,
    const float* __restrict__ tnear,
    const float* __restrict__ tfar,
    const float* __restrict__ noise,
    const float* __restrict__ W1,
    const float* __restrict__ b1,
    const float* __restrict__ w_sigma,
    const float* __restrict__ W_rgb,
    float* __restrict__ out)
{
    const int lane  = threadIdx.x & 63;   // ray within block (wave-coherent)
    const int chunk = threadIdx.x >> 6;   // 0..3 (one wave per chunk)
    const int ray   = blockIdx.x * RAYS_PER_BLOCK + lane;

    const int t0 = chunk * CHUNK_LEN;
    const float* __restrict__ nrow = noise + ray;

    // Issue the first noise loads immediately so their latency hides under setup.
    const float nz0 = nrow[(size_t)t0 * N_RAYS];
    float nzbuf[PF];
#pragma unroll
    for (int k = 0; k < PF; ++k)
        nzbuf[k] = nrow[(size_t)(t0 + 1 + k) * N_RAYS];

    // ---- per-ray setup (duplicated across the 4 chunk-waves; cheap) ----
    const float ox = o[ray*3+0], oy = o[ray*3+1], oz = o[ray*3+2];
    const float dx = d[ray*3+0], dy = d[ray*3+1], dz = d[ray*3+2];
    const float tn = tnear[ray];
    const float tf = tfar[ray];
    const float dnorm = sqrtf(dx*dx + dy*dy + dz*dz);
    const float rdn   = 1.0f / dnorm;
    const float sc    = (tf - tn) * (1.0f / (float)T_SAMPLES);

    // Work in scaled time u = ts*dnorm: delta*dnorm becomes a plain subtract.
    const float scd = sc * dnorm;
    const float tnd = tn * dnorm;
    const float uf  = tf * dnorm;

    // Hoisted MLP layer 1 in scaled time, packed in j-pairs:
    // h_j(u) = relu(A_j + u*Bp_j)
    v2f A2[HPAIR], B2[HPAIR];
    v2f WS2[HPAIR], WR2[HPAIR], WG2[HPAIR], WB2[HPAIR];
#pragma unroll
    for (int p = 0; p < HPAIR; ++p) {
#pragma unroll
        for (int h = 0; h < 2; ++h) {
            const int j = 2*p + h;
            const float w0 = W1[0*HID + j], w1 = W1[1*HID + j], w2 = W1[2*HID + j];
            A2[p][h] = fmaf(ox, w0, fmaf(oy, w1, fmaf(oz, w2, b1[j])));
            B2[p][h] = fmaf(dx, w0, fmaf(dy, w1, dz * w2)) * rdn;
            WS2[p][h] = w_sigma[j];
            WR2[p][h] = W_rgb[j*3+0];
            WG2[p][h] = W_rgb[j*3+1];
            WB2[p][h] = W_rgb[j*3+2];
        }
    }

    // ---- this thread's sample chunk [t0, t0+CHUNK_LEN) ----
    float u    = fmaf(scd, (float)t0 + nz0, tnd);   // ts0 * dnorm
    float base = fmaf(scd, (float)(t0 + 1), tnd);   // bin edge t+1 (scaled)

    float lt = 1.0f;   // local transmittance within chunk
    float cr = 0.f, cg = 0.f, cb = 0.f, cd = 0.f, ca = 0.f;

    for (int ii = 0; ii < CHUNK_LEN; ii += PF) {
#pragma unroll
        for (int k = 0; k < PF; ++k) {
            const int t = t0 + ii + k;               // wave-uniform

            // next sample position (scaled); final sample closes at tfar
            float u_next = fmaf(scd, nzbuf[k], base);
            if (t == T_SAMPLES - 1) u_next = uf;     // uniform -> 1 cndmask
            base += scd;

            // refill prefetch ring (clamped row; tail refills are harmless)
            int rrow = t + 1 + PF;
            if (rrow > T_SAMPLES - 1) rrow = T_SAMPLES - 1;
            nzbuf[k] = nrow[(size_t)rrow * N_RAYS];

            // packed MLP + 4 dots: v_pk_fma_f32 / v_pk_max_f32
            const v2f uu = { u, u };
            v2f sp2 = (v2f)0.f, rr2 = (v2f)0.f, gg2 = (v2f)0.f, bb2 = (v2f)0.f;
#pragma unroll
            for (int p = 0; p < HPAIR; ++p) {
                const v2f h2 = __builtin_elementwise_max(
                    __builtin_elementwise_fma(uu, B2[p], A2[p]), (v2f)0.f);
                sp2 = __builtin_elementwise_fma(h2, WS2[p], sp2);
                rr2 = __builtin_elementwise_fma(h2, WR2[p], rr2);
                gg2 = __builtin_elementwise_fma(h2, WG2[p], gg2);
                bb2 = __builtin_elementwise_fma(h2, WB2[p], bb2);
            }
            const float sp = sp2[0] + sp2[1];
            const float rr = rr2[0] + rr2[1];
            const float gg = gg2[0] + gg2[1];
            const float bb = bb2[0] + bb2[1];

            // l2 = log2(1 + exp(sp)) (stable softplus in base-2)
            const float e  = __builtin_amdgcn_exp2f(-fabsf(sp) * L2E);
            const float l2 = fmaf(fmaxf(sp, 0.0f), L2E,
                                  __builtin_amdgcn_logf(1.0f + e));
            const float dd = u_next - u;             // delta * dnorm
            const float et = __builtin_amdgcn_exp2f(-dd * l2);

            // sigmoids via base-2
            const float r = __builtin_amdgcn_rcpf(1.0f + __builtin_amdgcn_exp2f(-rr * L2E));
            const float g = __builtin_amdgcn_rcpf(1.0f + __builtin_amdgcn_exp2f(-gg * L2E));
            const float b = __builtin_amdgcn_rcpf(1.0f + __builtin_amdgcn_exp2f(-bb * L2E));

            const float w = fmaf(-et, lt, lt);       // lt * (1 - et)
            cr = fmaf(w, r, cr);
            cg = fmaf(w, g, cg);
            cb = fmaf(w, b, cb);
            cd = fmaf(w, u, cd);                     // scaled depth (u = ts*dnorm)
            ca += w;
            lt *= et;
            u = u_next;
        }
    }

    // ---- combine chunks: out_c scaled by product of previous chunks' lt ----
    __shared__ float s_lt[CHUNKS][RAYS_PER_BLOCK];
    __shared__ float s_acc[CHUNKS][5][RAYS_PER_BLOCK];
    s_lt[chunk][lane] = lt;
    s_acc[chunk][0][lane] = cr;
    s_acc[chunk][1][lane] = cg;
    s_acc[chunk][2][lane] = cb;
    s_acc[chunk][3][lane] = cd;
    s_acc[chunk][4][lane] = ca;
    __syncthreads();

    if (chunk == 0) {
        float scale = 1.0f;
        float a0 = 0.f, a1 = 0.f, a2 = 0.f, a3 = 0.f, a4 = 0.f;
#pragma unroll
        for (int c = 0; c < CHUNKS; ++c) {
            a0 = fmaf(scale, s_acc[c][0][lane], a0);
            a1 = fmaf(scale, s_acc[c][1][lane], a1);
            a2 = fmaf(scale, s_acc[c][2][lane], a2);
            a3 = fmaf(scale, s_acc[c][3][lane], a3);
            a4 = fmaf(scale, s_acc[c][4][lane], a4);
            scale *= s_lt[c][lane];
        }
        out[ray*5+0] = a0;
        out[ray*5+1] = a1;
        out[ray*5+2] = a2;
        out[ray*5+3] = a3 * rdn;   // un-scale depth back to ts units
        out[ray*5+4] = a4;
    }
}

extern "C" void kernel_launch(void* const* d_in, const int* in_sizes, int n_in,
                              void* d_out, int out_size, void* d_ws, size_t ws_size,
                              hipStream_t stream) {
    const float* o       = (const float*)d_in[0];
    const float* d       = (const float*)d_in[1];
    const float* tnear   = (const float*)d_in[2];
    const float* tfar    = (const float*)d_in[3];
    const float* noise   = (const float*)d_in[4];
    const float* W1      = (const float*)d_in[5];
    const float* b1      = (const float*)d_in[6];
    const float* w_sigma = (const float*)d_in[7];
    const float* W_rgb   = (const float*)d_in[8];
    float* out = (float*)d_out;

    dim3 block(64 * CHUNKS);                       // 256
    dim3 grid(N_RAYS / RAYS_PER_BLOCK);            // 1024
    hipLaunchKernelGGL(radiance_kernel, grid, block, 0, stream,
                       o, d, tnear, tfar, noise, W1, b1, w_sigma, W_rgb, out);
}